// Round 1
// baseline (367.256 us; speedup 1.0000x reference)
//
#include <hip/hip_runtime.h>

// GPT2 grouped-query attention, bf16 MFMA pipeline.
// B=4, S=2048, HID=1024, H=16, DH=64, G=1024, D'=128, SCALE=0.125.
// ws layout (bf16): q_att[64][1024][128] | k_att[64][1024][128] | v_t[64][128][1024] | ctx[8192][1024]

typedef __attribute__((ext_vector_type(8))) short short8;
typedef __attribute__((ext_vector_type(4))) float f32x4;
typedef unsigned int u32;
typedef unsigned short u16;

#define MFMA16(a, b, c) __builtin_amdgcn_mfma_f32_16x16x32_bf16((a), (b), (c), 0, 0, 0)

__device__ __forceinline__ u32 f2bf1(float x) {
    union { float f; u32 u; } v; v.f = x;
    return (v.u + 0x7fffu + ((v.u >> 16) & 1u)) >> 16;   // RNE
}

// ---------------------------------------------------------------------------
// Kernel 1: fused QKV projection. out = X @ W^T + b, scattered into attn layout.
// grid (8 n-tiles, 64 m-tiles, 3 matrices), 256 threads.
// ---------------------------------------------------------------------------
__global__ __launch_bounds__(256) void qkv_gemm(
    const float* __restrict__ X,
    const float* __restrict__ W0, const float* __restrict__ b0,
    const float* __restrict__ W1, const float* __restrict__ b1,
    const float* __restrict__ W2, const float* __restrict__ b2,
    u16* __restrict__ q_att, u16* __restrict__ k_att, u16* __restrict__ v_t)
{
    const int mat = blockIdx.z;
    const float* W    = (mat == 0) ? W0 : (mat == 1) ? W1 : W2;
    const float* bias = (mat == 0) ? b0 : (mat == 1) ? b1 : b2;
    const int mb = blockIdx.y, nb = blockIdx.x;

    __shared__ __align__(16) u16 As[128 * 40];   // stride 40: 2-way-free banks, 16B aligned rows
    __shared__ __align__(16) u16 Bs[128 * 40];

    const int t = threadIdx.x;
    const int wave = t >> 6, lane = t & 63, l15 = lane & 15, quad = lane >> 4;
    const int wm = (wave >> 1) * 64, wn = (wave & 1) * 64;

    f32x4 acc[4][4] = {};
    const float* Xa = X + (size_t)(mb * 128) * 1024;
    const float* Wa = W + (size_t)(nb * 128) * 1024;

    for (int k0 = 0; k0 < 1024; k0 += 32) {
        __syncthreads();
#pragma unroll
        for (int i = 0; i < 4; ++i) {
            int f = i * 256 + t, r = f >> 3, c4 = f & 7;
            float4 a = *(const float4*)(Xa + (size_t)r * 1024 + k0 + c4 * 4);
            uint2 d;
            d.x = f2bf1(a.x) | (f2bf1(a.y) << 16);
            d.y = f2bf1(a.z) | (f2bf1(a.w) << 16);
            *(uint2*)(As + r * 40 + c4 * 4) = d;
            float4 w = *(const float4*)(Wa + (size_t)r * 1024 + k0 + c4 * 4);
            uint2 e;
            e.x = f2bf1(w.x) | (f2bf1(w.y) << 16);
            e.y = f2bf1(w.z) | (f2bf1(w.w) << 16);
            *(uint2*)(Bs + r * 40 + c4 * 4) = e;
        }
        __syncthreads();

        short8 af[4], bf[4];
#pragma unroll
        for (int mt = 0; mt < 4; ++mt)
            af[mt] = *(const short8*)(As + (wm + mt * 16 + l15) * 40 + quad * 8);
#pragma unroll
        for (int nt = 0; nt < 4; ++nt)
            bf[nt] = *(const short8*)(Bs + (wn + nt * 16 + l15) * 40 + quad * 8);
#pragma unroll
        for (int mt = 0; mt < 4; ++mt)
#pragma unroll
            for (int nt = 0; nt < 4; ++nt)
                acc[mt][nt] = MFMA16(af[mt], bf[nt], acc[mt][nt]);
    }

    // epilogue: bias, scale (q), scatter to attention layout
#pragma unroll
    for (int nt = 0; nt < 4; ++nt) {
        int col = nb * 128 + wn + nt * 16 + l15;     // output feature = h*64+dh
        float bv = bias[col];
        int h = col >> 6, dh = col & 63;
#pragma unroll
        for (int mt = 0; mt < 4; ++mt) {
#pragma unroll
            for (int r = 0; r < 4; ++r) {
                int row = mb * 128 + wm + mt * 16 + quad * 4 + r;   // b*2048+s
                int b = row >> 11, s = row & 2047;
                int bh = b * 16 + h, g = s >> 1, dp = (s & 1) * 64 + dh;
                float v = acc[mt][nt][r] + bv;
                if (mat == 0)
                    q_att[((size_t)bh * 1024 + g) * 128 + dp] = (u16)f2bf1(v * 0.125f);
                else if (mat == 1)
                    k_att[((size_t)bh * 1024 + g) * 128 + dp] = (u16)f2bf1(v);
                else
                    v_t[((size_t)bh * 128 + dp) * 1024 + g] = (u16)f2bf1(v);
            }
        }
    }
}

// ---------------------------------------------------------------------------
// Kernel 2: flash attention per (b,h). grid (16 q-blocks of 64 rows, 64 bh), 256 thr.
// Each wave owns 16 q rows. K-tiles of 64 rows.
// ---------------------------------------------------------------------------
__global__ __launch_bounds__(256) void attn(
    const u16* __restrict__ q_att, const u16* __restrict__ k_att,
    const u16* __restrict__ v_t, u16* __restrict__ ctx)
{
    const int bh = blockIdx.y, qb = blockIdx.x;
    const u16* Q = q_att + (size_t)bh * 1024 * 128;
    const u16* K = k_att + (size_t)bh * 1024 * 128;
    const u16* V = v_t  + (size_t)bh * 128 * 1024;   // [d'=128][g=1024]

    __shared__ __align__(16) u16 Ks[64 * 136];   // [krow][d'], stride 136
    __shared__ __align__(16) u16 Vs[128 * 88];   // [d'][krow], stride 88
    __shared__ __align__(16) u16 Ps[4 * 16 * 88];// per-wave P [qrow][kcol], stride 88

    const int t = threadIdx.x, wave = t >> 6, lane = t & 63;
    const int l15 = lane & 15, quad = lane >> 4;
    const int g0 = qb * 64 + wave * 16;

    // Q fragments in registers (A-layout: m=l15 row, k = ks*32+quad*8+j)
    short8 aq[4];
#pragma unroll
    for (int ks = 0; ks < 4; ++ks)
        aq[ks] = *(const short8*)(Q + (size_t)(g0 + l15) * 128 + ks * 32 + quad * 8);

    f32x4 accO[8] = {};
    float m_i[4], l_i[4];
#pragma unroll
    for (int r = 0; r < 4; ++r) { m_i[r] = -3.0e38f; l_i[r] = 0.0f; }

    for (int kt = 0; kt < 16; ++kt) {
        __syncthreads();   // prev iter's K/V/P reads done
        // stage K tile (contiguous 16KB), coalesced uint4
        const u16* Ksrc = K + (size_t)kt * 64 * 128;
#pragma unroll
        for (int i = 0; i < 4; ++i) {
            int f = i * 256 + t, r = f >> 4, c8 = f & 15;
            uint4 d = *(const uint4*)(Ksrc + f * 8);
            *(uint4*)(Ks + r * 136 + c8 * 8) = d;
        }
        // stage V^T tile: rows d', 64 k-cols (128B per row, coalesced)
#pragma unroll
        for (int i = 0; i < 4; ++i) {
            int f = i * 256 + t, dp = f >> 3, c8 = f & 7;
            uint4 d = *(const uint4*)(V + (size_t)dp * 1024 + kt * 64 + c8 * 8);
            *(uint4*)(Vs + dp * 88 + c8 * 8) = d;
        }
        __syncthreads();

        // S = Q @ K^T   (16 x 64)
        f32x4 accS[4] = {};
#pragma unroll
        for (int nt = 0; nt < 4; ++nt)
#pragma unroll
            for (int ks = 0; ks < 4; ++ks) {
                short8 bk = *(const short8*)(Ks + (nt * 16 + l15) * 136 + ks * 32 + quad * 8);
                accS[nt] = MFMA16(aq[ks], bk, accS[nt]);
            }

        // online softmax (row = quad*4+r, col = nt*16+l15)
        float rmax[4];
#pragma unroll
        for (int r = 0; r < 4; ++r) {
            float m = accS[0][r];
#pragma unroll
            for (int nt = 1; nt < 4; ++nt) m = fmaxf(m, accS[nt][r]);
#pragma unroll
            for (int d = 1; d < 16; d <<= 1) m = fmaxf(m, __shfl_xor(m, d));
            rmax[r] = m;
        }
        float alpha[4];
#pragma unroll
        for (int r = 0; r < 4; ++r) {
            float mn = fmaxf(m_i[r], rmax[r]);
            alpha[r] = __expf(m_i[r] - mn);
            m_i[r] = mn;
        }
#pragma unroll
        for (int nt = 0; nt < 4; ++nt)
#pragma unroll
            for (int r = 0; r < 4; ++r)
                accS[nt][r] = __expf(accS[nt][r] - m_i[r]);
#pragma unroll
        for (int r = 0; r < 4; ++r) {
            float s = accS[0][r] + accS[1][r] + accS[2][r] + accS[3][r];
#pragma unroll
            for (int d = 1; d < 16; d <<= 1) s += __shfl_xor(s, d);
            l_i[r] = l_i[r] * alpha[r] + s;
        }
#pragma unroll
        for (int nt = 0; nt < 8; ++nt)
#pragma unroll
            for (int r = 0; r < 4; ++r) accO[nt][r] *= alpha[r];

        // P -> LDS (D-layout -> A-layout round trip)
        u16* Pw = Ps + wave * 16 * 88;
#pragma unroll
        for (int nt = 0; nt < 4; ++nt)
#pragma unroll
            for (int r = 0; r < 4; ++r)
                Pw[(quad * 4 + r) * 88 + nt * 16 + l15] = (u16)f2bf1(accS[nt][r]);
        __syncthreads();

        // O += P @ V   (16 x 128, k=64)
        short8 ap[2];
#pragma unroll
        for (int ks = 0; ks < 2; ++ks)
            ap[ks] = *(const short8*)(Pw + l15 * 88 + ks * 32 + quad * 8);
#pragma unroll
        for (int nt = 0; nt < 8; ++nt)
#pragma unroll
            for (int ks = 0; ks < 2; ++ks) {
                short8 bv = *(const short8*)(Vs + (nt * 16 + l15) * 88 + ks * 32 + quad * 8);
                accO[nt] = MFMA16(ap[ks], bv, accO[nt]);
            }
    }

    // epilogue: O/l -> ctx[b][s'=2g+(h>>3)][c=(h&7)*128+d'] in bf16
    const int h = bh & 15, b = bh >> 4;
    float inv[4];
#pragma unroll
    for (int r = 0; r < 4; ++r) inv[r] = 1.0f / l_i[r];
#pragma unroll
    for (int nt = 0; nt < 8; ++nt) {
        int dp = nt * 16 + l15;
        int c = (h & 7) * 128 + dp;
#pragma unroll
        for (int r = 0; r < 4; ++r) {
            int g = g0 + quad * 4 + r;
            int sp = 2 * g + (h >> 3);
            ctx[((size_t)(b * 2048 + sp)) * 1024 + c] = (u16)f2bf1(accO[nt][r] * inv[r]);
        }
    }
}

// ---------------------------------------------------------------------------
// Kernel 3: out = ctx(bf16) @ Wo^T + bo  -> fp32. grid (8,64), 256 thr.
// ---------------------------------------------------------------------------
__global__ __launch_bounds__(256) void out_gemm(
    const u16* __restrict__ ctx, const float* __restrict__ Wo,
    const float* __restrict__ bo, float* __restrict__ out)
{
    const int mb = blockIdx.y, nb = blockIdx.x;
    __shared__ __align__(16) u16 As[128 * 40];
    __shared__ __align__(16) u16 Bs[128 * 40];
    const int t = threadIdx.x;
    const int wave = t >> 6, lane = t & 63, l15 = lane & 15, quad = lane >> 4;
    const int wm = (wave >> 1) * 64, wn = (wave & 1) * 64;

    f32x4 acc[4][4] = {};
    const u16* Aa = ctx + (size_t)(mb * 128) * 1024;
    const float* Wa = Wo + (size_t)(nb * 128) * 1024;

    for (int k0 = 0; k0 < 1024; k0 += 32) {
        __syncthreads();
#pragma unroll
        for (int i = 0; i < 2; ++i) {
            int f = i * 256 + t, r = f >> 2, c8 = f & 3;
            uint4 d = *(const uint4*)(Aa + (size_t)r * 1024 + k0 + c8 * 8);
            *(uint4*)(As + r * 40 + c8 * 8) = d;
        }
#pragma unroll
        for (int i = 0; i < 4; ++i) {
            int f = i * 256 + t, r = f >> 3, c4 = f & 7;
            float4 w = *(const float4*)(Wa + (size_t)r * 1024 + k0 + c4 * 4);
            uint2 e;
            e.x = f2bf1(w.x) | (f2bf1(w.y) << 16);
            e.y = f2bf1(w.z) | (f2bf1(w.w) << 16);
            *(uint2*)(Bs + r * 40 + c4 * 4) = e;
        }
        __syncthreads();

        short8 af[4], bf[4];
#pragma unroll
        for (int mt = 0; mt < 4; ++mt)
            af[mt] = *(const short8*)(As + (wm + mt * 16 + l15) * 40 + quad * 8);
#pragma unroll
        for (int nt = 0; nt < 4; ++nt)
            bf[nt] = *(const short8*)(Bs + (wn + nt * 16 + l15) * 40 + quad * 8);
#pragma unroll
        for (int mt = 0; mt < 4; ++mt)
#pragma unroll
            for (int nt = 0; nt < 4; ++nt)
                acc[mt][nt] = MFMA16(af[mt], bf[nt], acc[mt][nt]);
    }

#pragma unroll
    for (int nt = 0; nt < 4; ++nt) {
        int col = nb * 128 + wn + nt * 16 + l15;
        float bv = bo[col];
#pragma unroll
        for (int mt = 0; mt < 4; ++mt)
#pragma unroll
            for (int r = 0; r < 4; ++r) {
                int row = mb * 128 + wm + mt * 16 + quad * 4 + r;
                out[(size_t)row * 1024 + col] = acc[mt][nt][r] + bv;
            }
    }
}

// ---------------------------------------------------------------------------
extern "C" void kernel_launch(void* const* d_in, const int* in_sizes, int n_in,
                              void* d_out, int out_size, void* d_ws, size_t ws_size,
                              hipStream_t stream)
{
    const float* X  = (const float*)d_in[0];
    const float* Wq = (const float*)d_in[1];
    const float* bq = (const float*)d_in[2];
    const float* Wk = (const float*)d_in[3];
    const float* bk = (const float*)d_in[4];
    const float* Wv = (const float*)d_in[5];
    const float* bv = (const float*)d_in[6];
    const float* Wo = (const float*)d_in[7];
    const float* bo = (const float*)d_in[8];

    u16* q_att = (u16*)d_ws;                               // 8M elems
    u16* k_att = q_att + (size_t)8 * 1024 * 1024;
    u16* v_t   = k_att + (size_t)8 * 1024 * 1024;
    u16* ctx   = v_t   + (size_t)8 * 1024 * 1024;

    qkv_gemm<<<dim3(8, 64, 3), 256, 0, stream>>>(X, Wq, bq, Wk, bk, Wv, bv,
                                                 q_att, k_att, v_t);
    attn<<<dim3(16, 64), 256, 0, stream>>>(q_att, k_att, v_t, ctx);
    out_gemm<<<dim3(8, 64), 256, 0, stream>>>(ctx, Wo, bo, (float*)d_out);
}

// Round 2
// 306.765 us; speedup vs baseline: 1.1972x; 1.1972x over previous
//
#include <hip/hip_runtime.h>

// GPT2 grouped-query attention, bf16 MFMA pipeline, round 1.
// B=4, S=2048, HID=1024, H=16, DH=64, G=1024, D'=128, SCALE=0.125.
// ws (u16 elems): q_att[8M] | k_att[8M] | v_t[8M] | Xb/ctx[8M] | Wcat[3M] | Wob[1M]  = 72MB

typedef __attribute__((ext_vector_type(8))) short short8;
typedef __attribute__((ext_vector_type(4))) float f32x4;
typedef unsigned int u32;
typedef unsigned short u16;

#define MFMA16(a, b, c) __builtin_amdgcn_mfma_f32_16x16x32_bf16((a), (b), (c), 0, 0, 0)

__device__ __forceinline__ u32 f2bf1(float x) {
    union { float f; u32 u; } v; v.f = x;
    return (v.u + 0x7fffu + ((v.u >> 16) & 1u)) >> 16;   // RNE
}

// async global->LDS, 16B per lane; LDS dest must be wave-uniform base (+lane*16)
__device__ __forceinline__ void gld16(u16* lds, const u16* g) {
    __builtin_amdgcn_global_load_lds(
        (const __attribute__((address_space(1))) unsigned int*)(g),
        (__attribute__((address_space(3))) unsigned int*)(lds),
        16, 0, 0);
}

// ---------------------------------------------------------------------------
// Kernel 0: fp32 -> bf16 convert. X(8M) | Wq|Wk|Wv -> Wcat(3M) | Wo -> Wob(1M).
// 3072 blocks x 256 thr x 16 floats = 12,582,912 floats exactly.
// ---------------------------------------------------------------------------
__global__ __launch_bounds__(256) void convert(
    const float* __restrict__ X, const float* __restrict__ Wq,
    const float* __restrict__ Wk, const float* __restrict__ Wv,
    const float* __restrict__ Wo,
    u16* __restrict__ Xb, u16* __restrict__ Wcat, u16* __restrict__ Wob)
{
    const size_t M8 = 8388608, M1 = 1048576;
    size_t i = ((size_t)blockIdx.x * 256 + threadIdx.x) * 16;
    const float* src; u16* dst;
    if (i < M8)              { src = X  + i;                dst = Xb   + i; }
    else if (i < M8 + M1)    { src = Wq + (i - M8);         dst = Wcat + (i - M8); }
    else if (i < M8 + 2*M1)  { src = Wk + (i - M8 - M1);    dst = Wcat + (i - M8); }
    else if (i < M8 + 3*M1)  { src = Wv + (i - M8 - 2*M1);  dst = Wcat + (i - M8); }
    else                     { src = Wo + (i - M8 - 3*M1);  dst = Wob  + (i - M8 - 3*M1); }
#pragma unroll
    for (int j = 0; j < 2; ++j) {
        float4 a = ((const float4*)src)[2 * j];
        float4 b = ((const float4*)src)[2 * j + 1];
        uint4 o;
        o.x = f2bf1(a.x) | (f2bf1(a.y) << 16);
        o.y = f2bf1(a.z) | (f2bf1(a.w) << 16);
        o.z = f2bf1(b.x) | (f2bf1(b.y) << 16);
        o.w = f2bf1(b.z) | (f2bf1(b.w) << 16);
        ((uint4*)dst)[j] = o;
    }
}

// ---------------------------------------------------------------------------
// Kernel 1: fused QKV GEMM (m97 structure). C[8192][3072] = Xb @ Wcat^T.
// grid (24 n-tiles, 64 m-tiles), 256 thr. 128x128 tile, BK=32, global_load_lds.
// Epilogue: +bias, q-scale, scatter to attention layouts.
// ---------------------------------------------------------------------------
__global__ __launch_bounds__(256) void qkv_gemm2(
    const u16* __restrict__ Xb, const u16* __restrict__ Wcat,
    const float* __restrict__ b0, const float* __restrict__ b1,
    const float* __restrict__ b2,
    u16* __restrict__ q_att, u16* __restrict__ k_att, u16* __restrict__ v_t)
{
    const int nb = blockIdx.x, mb = blockIdx.y;
    const int mat = nb >> 3;

    __shared__ __align__(16) u16 As[128 * 32];   // unpadded: global_load_lds layout
    __shared__ __align__(16) u16 Bs[128 * 32];

    const int t = threadIdx.x, wave = t >> 6, lane = t & 63;
    const int l15 = lane & 15, quad = lane >> 4;
    const int wm = (wave >> 1) * 64, wn = (wave & 1) * 64;
    const int lrow = lane >> 2, lcb = (lane & 3) * 8;

    const u16* Ab = Xb   + (size_t)(mb * 128) * 1024;
    const u16* Bb = Wcat + (size_t)(nb * 128) * 1024;

    f32x4 acc[4][4] = {};

    for (int k0 = 0; k0 < 1024; k0 += 32) {
        __syncthreads();
#pragma unroll
        for (int j = 0; j < 2; ++j) {
            int chunk = wave * 2 + j;            // 16 rows per 1KB chunk
            gld16(As + chunk * 512, Ab + (size_t)(chunk * 16 + lrow) * 1024 + k0 + lcb);
            gld16(Bs + chunk * 512, Bb + (size_t)(chunk * 16 + lrow) * 1024 + k0 + lcb);
        }
        __syncthreads();

        short8 af[4], bf[4];
#pragma unroll
        for (int mt = 0; mt < 4; ++mt)
            af[mt] = *(const short8*)(As + (wm + mt * 16 + l15) * 32 + quad * 8);
#pragma unroll
        for (int nt = 0; nt < 4; ++nt)
            bf[nt] = *(const short8*)(Bs + (wn + nt * 16 + l15) * 32 + quad * 8);
#pragma unroll
        for (int mt = 0; mt < 4; ++mt)
#pragma unroll
            for (int nt = 0; nt < 4; ++nt)
                acc[mt][nt] = MFMA16(af[mt], bf[nt], acc[mt][nt]);
    }

    const float* bias = (mat == 0) ? b0 : (mat == 1) ? b1 : b2;
#pragma unroll
    for (int nt = 0; nt < 4; ++nt) {
        int colm = (nb & 7) * 128 + wn + nt * 16 + l15;   // feature = h*64+dh
        float bv = bias[colm];
        int h = colm >> 6, dh = colm & 63;
#pragma unroll
        for (int mt = 0; mt < 4; ++mt) {
#pragma unroll
            for (int r = 0; r < 4; ++r) {
                int row = mb * 128 + wm + mt * 16 + quad * 4 + r;   // b*2048+s
                int b = row >> 11, s = row & 2047;
                int bh = b * 16 + h, g = s >> 1, dp = (s & 1) * 64 + dh;
                float v = acc[mt][nt][r] + bv;
                if (mat == 0)
                    q_att[((size_t)bh * 1024 + g) * 128 + dp] = (u16)f2bf1(v * 0.125f);
                else if (mat == 1)
                    k_att[((size_t)bh * 1024 + g) * 128 + dp] = (u16)f2bf1(v);
                else
                    v_t[((size_t)bh * 128 + dp) * 1024 + g] = (u16)f2bf1(v);
            }
        }
    }
}

// ---------------------------------------------------------------------------
// Kernel 2: flash attention per (b,h). grid (16 q-blocks of 64 rows, 64 bh), 256 thr.
// (unchanged from round 0)
// ---------------------------------------------------------------------------
__global__ __launch_bounds__(256) void attn(
    const u16* __restrict__ q_att, const u16* __restrict__ k_att,
    const u16* __restrict__ v_t, u16* __restrict__ ctx)
{
    const int bh = blockIdx.y, qb = blockIdx.x;
    const u16* Q = q_att + (size_t)bh * 1024 * 128;
    const u16* K = k_att + (size_t)bh * 1024 * 128;
    const u16* V = v_t  + (size_t)bh * 128 * 1024;   // [d'=128][g=1024]

    __shared__ __align__(16) u16 Ks[64 * 136];
    __shared__ __align__(16) u16 Vs[128 * 88];
    __shared__ __align__(16) u16 Ps[4 * 16 * 88];

    const int t = threadIdx.x, wave = t >> 6, lane = t & 63;
    const int l15 = lane & 15, quad = lane >> 4;
    const int g0 = qb * 64 + wave * 16;

    short8 aq[4];
#pragma unroll
    for (int ks = 0; ks < 4; ++ks)
        aq[ks] = *(const short8*)(Q + (size_t)(g0 + l15) * 128 + ks * 32 + quad * 8);

    f32x4 accO[8] = {};
    float m_i[4], l_i[4];
#pragma unroll
    for (int r = 0; r < 4; ++r) { m_i[r] = -3.0e38f; l_i[r] = 0.0f; }

    for (int kt = 0; kt < 16; ++kt) {
        __syncthreads();
        const u16* Ksrc = K + (size_t)kt * 64 * 128;
#pragma unroll
        for (int i = 0; i < 4; ++i) {
            int f = i * 256 + t, r = f >> 4, c8 = f & 15;
            uint4 d = *(const uint4*)(Ksrc + f * 8);
            *(uint4*)(Ks + r * 136 + c8 * 8) = d;
        }
#pragma unroll
        for (int i = 0; i < 4; ++i) {
            int f = i * 256 + t, dp = f >> 3, c8 = f & 7;
            uint4 d = *(const uint4*)(V + (size_t)dp * 1024 + kt * 64 + c8 * 8);
            *(uint4*)(Vs + dp * 88 + c8 * 8) = d;
        }
        __syncthreads();

        f32x4 accS[4] = {};
#pragma unroll
        for (int nt = 0; nt < 4; ++nt)
#pragma unroll
            for (int ks = 0; ks < 4; ++ks) {
                short8 bk = *(const short8*)(Ks + (nt * 16 + l15) * 136 + ks * 32 + quad * 8);
                accS[nt] = MFMA16(aq[ks], bk, accS[nt]);
            }

        float rmax[4];
#pragma unroll
        for (int r = 0; r < 4; ++r) {
            float m = accS[0][r];
#pragma unroll
            for (int nt = 1; nt < 4; ++nt) m = fmaxf(m, accS[nt][r]);
#pragma unroll
            for (int d = 1; d < 16; d <<= 1) m = fmaxf(m, __shfl_xor(m, d));
            rmax[r] = m;
        }
        float alpha[4];
#pragma unroll
        for (int r = 0; r < 4; ++r) {
            float mn = fmaxf(m_i[r], rmax[r]);
            alpha[r] = __expf(m_i[r] - mn);
            m_i[r] = mn;
        }
#pragma unroll
        for (int nt = 0; nt < 4; ++nt)
#pragma unroll
            for (int r = 0; r < 4; ++r)
                accS[nt][r] = __expf(accS[nt][r] - m_i[r]);
#pragma unroll
        for (int r = 0; r < 4; ++r) {
            float s = accS[0][r] + accS[1][r] + accS[2][r] + accS[3][r];
#pragma unroll
            for (int d = 1; d < 16; d <<= 1) s += __shfl_xor(s, d);
            l_i[r] = l_i[r] * alpha[r] + s;
        }
#pragma unroll
        for (int nt = 0; nt < 8; ++nt)
#pragma unroll
            for (int r = 0; r < 4; ++r) accO[nt][r] *= alpha[r];

        u16* Pw = Ps + wave * 16 * 88;
#pragma unroll
        for (int nt = 0; nt < 4; ++nt)
#pragma unroll
            for (int r = 0; r < 4; ++r)
                Pw[(quad * 4 + r) * 88 + nt * 16 + l15] = (u16)f2bf1(accS[nt][r]);
        __syncthreads();

        short8 ap[2];
#pragma unroll
        for (int ks = 0; ks < 2; ++ks)
            ap[ks] = *(const short8*)(Pw + l15 * 88 + ks * 32 + quad * 8);
#pragma unroll
        for (int nt = 0; nt < 8; ++nt)
#pragma unroll
            for (int ks = 0; ks < 2; ++ks) {
                short8 bv = *(const short8*)(Vs + (nt * 16 + l15) * 88 + ks * 32 + quad * 8);
                accO[nt] = MFMA16(ap[ks], bv, accO[nt]);
            }
    }

    const int h = bh & 15, b = bh >> 4;
    float inv[4];
#pragma unroll
    for (int r = 0; r < 4; ++r) inv[r] = 1.0f / l_i[r];
#pragma unroll
    for (int nt = 0; nt < 8; ++nt) {
        int dp = nt * 16 + l15;
        int c = (h & 7) * 128 + dp;
#pragma unroll
        for (int r = 0; r < 4; ++r) {
            int g = g0 + quad * 4 + r;
            int sp = 2 * g + (h >> 3);
            ctx[((size_t)(b * 2048 + sp)) * 1024 + c] = (u16)f2bf1(accO[nt][r] * inv[r]);
        }
    }
}

// ---------------------------------------------------------------------------
// Kernel 3: out = ctx(bf16) @ Wob^T + bo -> fp32 (m97 structure). grid (8,64).
// ---------------------------------------------------------------------------
__global__ __launch_bounds__(256) void out_gemm2(
    const u16* __restrict__ ctx, const u16* __restrict__ Wob,
    const float* __restrict__ bo, float* __restrict__ out)
{
    const int nb = blockIdx.x, mb = blockIdx.y;
    __shared__ __align__(16) u16 As[128 * 32];
    __shared__ __align__(16) u16 Bs[128 * 32];
    const int t = threadIdx.x, wave = t >> 6, lane = t & 63;
    const int l15 = lane & 15, quad = lane >> 4;
    const int wm = (wave >> 1) * 64, wn = (wave & 1) * 64;
    const int lrow = lane >> 2, lcb = (lane & 3) * 8;

    const u16* Ab = ctx + (size_t)(mb * 128) * 1024;
    const u16* Bb = Wob + (size_t)(nb * 128) * 1024;

    f32x4 acc[4][4] = {};

    for (int k0 = 0; k0 < 1024; k0 += 32) {
        __syncthreads();
#pragma unroll
        for (int j = 0; j < 2; ++j) {
            int chunk = wave * 2 + j;
            gld16(As + chunk * 512, Ab + (size_t)(chunk * 16 + lrow) * 1024 + k0 + lcb);
            gld16(Bs + chunk * 512, Bb + (size_t)(chunk * 16 + lrow) * 1024 + k0 + lcb);
        }
        __syncthreads();

        short8 af[4], bf[4];
#pragma unroll
        for (int mt = 0; mt < 4; ++mt)
            af[mt] = *(const short8*)(As + (wm + mt * 16 + l15) * 32 + quad * 8);
#pragma unroll
        for (int nt = 0; nt < 4; ++nt)
            bf[nt] = *(const short8*)(Bs + (wn + nt * 16 + l15) * 32 + quad * 8);
#pragma unroll
        for (int mt = 0; mt < 4; ++mt)
#pragma unroll
            for (int nt = 0; nt < 4; ++nt)
                acc[mt][nt] = MFMA16(af[mt], bf[nt], acc[mt][nt]);
    }

#pragma unroll
    for (int nt = 0; nt < 4; ++nt) {
        int col = nb * 128 + wn + nt * 16 + l15;
        float bv = bo[col];
#pragma unroll
        for (int mt = 0; mt < 4; ++mt)
#pragma unroll
            for (int r = 0; r < 4; ++r) {
                int row = mb * 128 + wm + mt * 16 + quad * 4 + r;
                out[(size_t)row * 1024 + col] = acc[mt][nt][r] + bv;
            }
    }
}

// ---------------------------------------------------------------------------
extern "C" void kernel_launch(void* const* d_in, const int* in_sizes, int n_in,
                              void* d_out, int out_size, void* d_ws, size_t ws_size,
                              hipStream_t stream)
{
    const float* X  = (const float*)d_in[0];
    const float* Wq = (const float*)d_in[1];
    const float* bq = (const float*)d_in[2];
    const float* Wk = (const float*)d_in[3];
    const float* bk = (const float*)d_in[4];
    const float* Wv = (const float*)d_in[5];
    const float* bv = (const float*)d_in[6];
    const float* Wo = (const float*)d_in[7];
    const float* bo = (const float*)d_in[8];

    const size_t M8 = 8388608;
    u16* q_att = (u16*)d_ws;            // 8M u16
    u16* k_att = q_att + M8;
    u16* v_t   = k_att + M8;
    u16* Xb    = v_t   + M8;            // Xb dead after qkv -> ctx aliases it
    u16* ctx   = Xb;
    u16* Wcat  = Xb + M8;               // 3M u16
    u16* Wob   = Wcat + 3 * 1048576;    // 1M u16

    convert<<<dim3(3072), 256, 0, stream>>>(X, Wq, Wk, Wv, Wo, Xb, Wcat, Wob);
    qkv_gemm2<<<dim3(24, 64), 256, 0, stream>>>(Xb, Wcat, bq, bk, bv,
                                                q_att, k_att, v_t);
    attn<<<dim3(16, 64), 256, 0, stream>>>(q_att, k_att, v_t, ctx);
    out_gemm2<<<dim3(8, 64), 256, 0, stream>>>(ctx, Wob, bo, (float*)d_out);
}